// Round 1
// baseline (651.951 us; speedup 1.0000x reference)
//
#include <hip/hip_runtime.h>
#include <hip/hip_bf16.h>
#include <stdint.h>

typedef __attribute__((ext_vector_type(8))) short short8;
typedef __attribute__((ext_vector_type(4))) float f32x4;

#define T_STEPS 10
#define BT 32                                   // batch rows per block
#define WPACK_CHUNKS (4*32*16*64)               // [g][jt][kc][lane] 16B chunks
#define WPACK_BYTES  (WPACK_CHUNKS*16)          // 2 MiB

__device__ __forceinline__ unsigned int pk2(float x, float y){
  unsigned int bx = __float_as_uint(x), by = __float_as_uint(y);
  bx = (bx + 0x7FFFu + ((bx>>16)&1u)) >> 16;     // RNE fp32->bf16
  by = (by + 0x7FFFu + ((by>>16)&1u)) >> 16;
  return bx | (by<<16);
}
__device__ __forceinline__ float sigf(float x){ return 1.f/(1.f + __expf(-x)); }
__device__ __forceinline__ float tanh_(float x){
  x = fminf(fmaxf(x, -15.f), 15.f);
  float e = __expf(2.f*x);
  return (e - 1.f)/(e + 1.f);
}

// ---- K0a: pack W_hh [2048][512] fp32 -> bf16 B-fragment order -------------
__global__ __launch_bounds__(256) void k_pack(const float* __restrict__ Whh,
                                              unsigned short* __restrict__ wp){
  int id  = blockIdx.x*256 + threadIdx.x;   // 0..131071
  int row = id >> 6;                        // gate col 0..2047
  int ko  = (id & 63) * 8;                  // k offset 0..504
  const float* p = Whh + row*512 + ko;
  float4 a = *(const float4*)p, b = *(const float4*)(p+4);
  uint4 v;
  v.x = pk2(a.x,a.y); v.y = pk2(a.z,a.w);
  v.z = pk2(b.x,b.y); v.w = pk2(b.z,b.w);
  int g = row >> 9, jin = row & 511, jt = jin >> 4, jl = jin & 15;
  int kc = ko >> 5, khi = (ko >> 3) & 3, lane = khi*16 + jl;
  int chunk = ((g*32 + jt)*16 + kc)*64 + lane;
  *(uint4*)(wp + chunk*8) = v;
}

// ---- K0b: v[j] = sum_h fc2[h]*fc1[h][j]; bias0 = fc2.fc1_b + fc2_b --------
__global__ __launch_bounds__(256) void k_v(const float* __restrict__ fc1w,
                                           const float* __restrict__ fc1b,
                                           const float* __restrict__ fc2w,
                                           const float* __restrict__ fc2b,
                                           float* __restrict__ vout,
                                           float* __restrict__ bias0){
  __shared__ float red[4][64];
  int tid = threadIdx.x;
  if (blockIdx.x < 16){
    int j  = blockIdx.x*64 + (tid & 63);
    int hc = tid >> 6;
    float s = 0.f;
    for (int hh = hc*128; hh < hc*128 + 128; ++hh)
      s += fc2w[hh] * fc1w[hh*1024 + j];
    red[hc][tid & 63] = s;
    __syncthreads();
    if (tid < 64)
      vout[blockIdx.x*64 + tid] = red[0][tid]+red[1][tid]+red[2][tid]+red[3][tid];
  } else {
    if (tid < 64){
      float s = 0.f;
      for (int i = 0; i < 8; ++i){ int hh = i*64 + tid; s += fc2w[hh]*fc1b[hh]; }
      for (int m = 32; m; m >>= 1) s += __shfl_xor(s, m);
      if (tid == 0) *bias0 = s + fc2b[0];
    }
  }
}

// ---- K2: out[b] = h[b,9,:].v2 + bias0 (overwrites -> deterministic init) --
__global__ __launch_bounds__(512) void k_init(const float* __restrict__ h,
                                              const float* __restrict__ v,
                                              const float* __restrict__ bias0,
                                              float* __restrict__ out){
  int w = threadIdx.x >> 6, lane = threadIdx.x & 63;
  float b0v = *bias0;
  const float* v2 = v + 512;
  for (int r = 0; r < 8; ++r){
    int b = blockIdx.x*64 + w*8 + r;
    const float* hp = h + ((size_t)b*T_STEPS + 9)*512 + lane*8;
    float4 x0 = *(const float4*)hp, x1 = *(const float4*)(hp+4);
    const float* vp = v2 + lane*8;
    float4 w0 = *(const float4*)vp, w1 = *(const float4*)(vp+4);
    float s = x0.x*w0.x + x0.y*w0.y + x0.z*w0.z + x0.w*w0.w
            + x1.x*w1.x + x1.y*w1.y + x1.z*w1.z + x1.w*w1.w;
    for (int m = 32; m; m >>= 1) s += __shfl_xor(s, m);
    if (lane == 0) out[b] = s + b0v;
  }
}

// ---- K1 helper: one n-half GEMM + cell update ------------------------------
template<int NG, int N0>
__device__ __forceinline__ void gemm_step(
    const unsigned short* As, const short8* wp, int w, int lane,
    const float (&yv)[2][4], const float (&bias2)[4][4], const float (&wihv)[4][4],
    const float (&v1v)[4], float (&cst)[2][4][4], float (&part)[2][4])
{
  int lhi = lane >> 4, llo = lane & 15;
  f32x4 acc[2][NG][2];
#pragma unroll
  for (int m=0;m<2;++m)
#pragma unroll
    for (int g=0;g<NG;++g)
#pragma unroll
      for (int n=0;n<2;++n) acc[m][g][n] = (f32x4){0.f,0.f,0.f,0.f};

  int koff = lhi*8;
  int sw = (llo & 7) << 3;
#pragma unroll 4
  for (int kc=0; kc<16; ++kc){
    int ko = kc*32 + koff;
    short8 a0 = *(const short8*)&As[ llo     *512 + (ko ^ sw)];
    short8 a1 = *(const short8*)&As[(llo+16)*512 + (ko ^ sw)];
#pragma unroll
    for (int g=0; g<NG; ++g){
#pragma unroll
      for (int n=0; n<2; ++n){
        int jt = w*4 + N0 + n;
        short8 bf = wp[((g*32 + jt)*16 + kc)*64 + lane];
        acc[0][g][n] = __builtin_amdgcn_mfma_f32_16x16x32_bf16(a0, bf, acc[0][g][n], 0, 0, 0);
        acc[1][g][n] = __builtin_amdgcn_mfma_f32_16x16x32_bf16(a1, bf, acc[1][g][n], 0, 0, 0);
      }
    }
  }
#pragma unroll
  for (int m=0;m<2;++m)
#pragma unroll
    for (int n=0;n<2;++n){
      int gn = N0 + n;
#pragma unroll
      for (int r=0;r<4;++r){
        float gi = acc[m][0][n][r] + fmaf(yv[m][r], wihv[0][gn], bias2[0][gn]);
        float gf = acc[m][1][n][r] + fmaf(yv[m][r], wihv[1][gn], bias2[1][gn]);
        float gg = acc[m][2][n][r] + fmaf(yv[m][r], wihv[2][gn], bias2[2][gn]);
        float c  = sigf(gf)*cst[m][gn][r] + sigf(gi)*tanh_(gg);
        cst[m][gn][r] = c;
        if (NG == 4){
          float go = acc[m][3][n][r] + fmaf(yv[m][r], wihv[3][gn], bias2[3][gn]);
          part[m][r] += sigf(go)*tanh_(c)*v1v[gn];
        }
      }
    }
}

// ---- K1: fused gates GEMM + LSTM scan + d.v1 contribution ------------------
__global__ __launch_bounds__(512, 2) void k_main(
    const float* __restrict__ h, const float* __restrict__ y,
    const float* __restrict__ Wih, const float* __restrict__ bih,
    const float* __restrict__ bhh,
    const unsigned short* __restrict__ wpack_us, const float* __restrict__ v1,
    float* __restrict__ out)
{
  __shared__ __align__(16) unsigned short As[BT*512];
  const short8* wp = (const short8*)wpack_us;
  int tid = threadIdx.x;
  int w = tid >> 6, lane = tid & 63, lhi = lane >> 4, llo = lane & 15;
  int b0 = blockIdx.x * BT;

  float bias2[4][4], wihv[4][4], v1v[4];
#pragma unroll
  for (int g=0;g<4;++g)
#pragma unroll
    for (int n=0;n<4;++n){
      int col = g*512 + (w*4+n)*16 + llo;
      bias2[g][n] = bih[col] + bhh[col];
      wihv[g][n]  = Wih[col];
    }
#pragma unroll
  for (int n=0;n<4;++n) v1v[n] = v1[(w*4+n)*16 + llo];

  float cst[2][4][4];
  float part[2][4];
#pragma unroll
  for (int m=0;m<2;++m){
#pragma unroll
    for (int n=0;n<4;++n)
#pragma unroll
      for (int r=0;r<4;++r) cst[m][n][r] = 0.f;
#pragma unroll
    for (int r=0;r<4;++r) part[m][r] = 0.f;
  }

#pragma unroll 1
  for (int t=0; t<T_STEPS; ++t){
    __syncthreads();
#pragma unroll
    for (int i=0;i<4;++i){
      int cid = tid + i*512;
      int row = cid >> 6, ko = (cid & 63)*8;
      const float* hp = h + ((size_t)(b0+row)*T_STEPS + t)*512 + ko;
      float4 x0 = *(const float4*)hp, x1 = *(const float4*)(hp+4);
      uint4 pkv;
      pkv.x = pk2(x0.x,x0.y); pkv.y = pk2(x0.z,x0.w);
      pkv.z = pk2(x1.x,x1.y); pkv.w = pk2(x1.z,x1.w);
      *(uint4*)&As[row*512 + (ko ^ ((row&7)<<3))] = pkv;
    }
    __syncthreads();

    float yv[2][4];
#pragma unroll
    for (int m=0;m<2;++m)
#pragma unroll
      for (int r=0;r<4;++r)
        yv[m][r] = y[(size_t)(b0 + m*16 + lhi*4 + r)*T_STEPS + t];

    if (t == T_STEPS-1){
      gemm_step<4,0>(As, wp, w, lane, yv, bias2, wihv, v1v, cst, part);
      gemm_step<4,2>(As, wp, w, lane, yv, bias2, wihv, v1v, cst, part);
    } else {
      gemm_step<3,0>(As, wp, w, lane, yv, bias2, wihv, v1v, cst, part);
      gemm_step<3,2>(As, wp, w, lane, yv, bias2, wihv, v1v, cst, part);
    }
  }

#pragma unroll
  for (int m=0;m<2;++m)
#pragma unroll
    for (int r=0;r<4;++r){
      float val = part[m][r];
      val += __shfl_xor(val, 1);
      val += __shfl_xor(val, 2);
      val += __shfl_xor(val, 4);
      val += __shfl_xor(val, 8);
      if (llo == 0) atomicAdd(&out[b0 + m*16 + lhi*4 + r], val);
    }
}

extern "C" void kernel_launch(void* const* d_in, const int* in_sizes, int n_in,
                              void* d_out, int out_size, void* d_ws, size_t ws_size,
                              hipStream_t stream){
  (void)in_sizes; (void)n_in; (void)out_size; (void)ws_size;
  const float* h    = (const float*)d_in[0];
  const float* y    = (const float*)d_in[1];
  // d_in[2..7] = attn1_w/b, attn2_w/b, attn3_w/b : mathematically dead (softmax over size-1 dim == 1)
  const float* Wih  = (const float*)d_in[8];
  const float* Whh  = (const float*)d_in[9];
  const float* bih  = (const float*)d_in[10];
  const float* bhh  = (const float*)d_in[11];
  const float* fc1w = (const float*)d_in[12];
  const float* fc1b = (const float*)d_in[13];
  const float* fc2w = (const float*)d_in[14];
  const float* fc2b = (const float*)d_in[15];
  float* out = (float*)d_out;

  unsigned short* wpack = (unsigned short*)d_ws;
  float* vbuf  = (float*)((char*)d_ws + WPACK_BYTES);
  float* bias0 = vbuf + 1024;

  k_pack<<<512, 256, 0, stream>>>(Whh, wpack);
  k_v<<<17, 256, 0, stream>>>(fc1w, fc1b, fc2w, fc2b, vbuf, bias0);
  k_init<<<128, 512, 0, stream>>>(h, vbuf, bias0, out);
  k_main<<<256, 512, 0, stream>>>(h, y, Wih, bih, bhh, wpack, vbuf, out);
}